// Round 6
// baseline (1555.243 us; speedup 1.0000x reference)
//
#include <hip/hip_runtime.h>
#include <stdint.h>

#define B_ 32
#define S_ 512
#define I_ 256
#define H_ 512
#define OUTW 1024
#define OUTS_ELEMS (B_*S_*OUTW)   // 16777216

typedef _Float16 f16;
typedef _Float16 half2_t __attribute__((ext_vector_type(2)));

__device__ __forceinline__ float fdot2(uint32_t a, uint32_t b, float c){
#if __has_builtin(__builtin_amdgcn_fdot2)
  return __builtin_amdgcn_fdot2(__builtin_bit_cast(half2_t, a),
                                __builtin_bit_cast(half2_t, b), c, false);
#else
  half2_t ha = __builtin_bit_cast(half2_t, a);
  half2_t hb = __builtin_bit_cast(half2_t, b);
  return c + (float)ha.x*(float)hb.x + (float)ha.y*(float)hb.y;
#endif
}

__device__ __forceinline__ uint32_t packf16(float x, float y){
  union { f16 h[2]; uint32_t u; } z;
  z.h[0] = (f16)x; z.h[1] = (f16)y;
  return z.u;
}

template<int CTRL>
__device__ __forceinline__ float dpp_xor_add(float x){
  int v = __builtin_amdgcn_update_dpp(0, __float_as_int(x), CTRL, 0xF, 0xF, true);
  return x + __int_as_float(v);
}

// 8-lane (sl group) reduce of 4 accs; lane gets total for acc index (sl&3)
__device__ __forceinline__ float reduce8(float a0, float a1, float a2, float a3, int k3){
  a0 = dpp_xor_add<0xB1>(a0); a1 = dpp_xor_add<0xB1>(a1);
  a2 = dpp_xor_add<0xB1>(a2); a3 = dpp_xor_add<0xB1>(a3);
  a0 = dpp_xor_add<0x4E>(a0); a1 = dpp_xor_add<0x4E>(a1);
  a2 = dpp_xor_add<0x4E>(a2); a3 = dpp_xor_add<0x4E>(a3);
  float own = (k3==0)?a0:(k3==1)?a1:(k3==2)?a2:a3;
  return own + __shfl_xor(own, 4);
}

// ---------------------------------------------------------------------------
// P0: W_hh fp32 -> f16 into d_ws
// ---------------------------------------------------------------------------
__global__ __launch_bounds__(256) void cvt_w_kernel(const float* __restrict__ wf,
                                                    const float* __restrict__ wb,
                                                    f16* __restrict__ out){
  int i = blockIdx.x*256 + threadIdx.x;
  const float* src = (i < 32768) ? wf : wb;
  int base = (i & 32767) * 8;
  float4 a = *(const float4*)(src + base);
  float4 c = *(const float4*)(src + base + 4);
  uint4 o;
  o.x = packf16(a.x, a.y); o.y = packf16(a.z, a.w);
  o.z = packf16(c.x, c.y); o.w = packf16(c.z, c.w);
  *(uint4*)(out + (size_t)i*8) = o;
}

// ---------------------------------------------------------------------------
// P1: xp staged into d_out (read once by rnn, then overwritten with h).
// ---------------------------------------------------------------------------
#define PTM 128
#define PTN 64
#define PTK 32
__global__ __launch_bounds__(256) void proj_kernel(
    const float* __restrict__ x,
    const float* __restrict__ wihf, const float* __restrict__ wihb,
    const float* __restrict__ bihf, const float* __restrict__ bhhf,
    const float* __restrict__ bihb, const float* __restrict__ bhhb,
    float* __restrict__ out)
{
  __shared__ float As[PTK][132];
  __shared__ float Bs[PTK][68];
  const int tid = threadIdx.x;
  const int row0 = blockIdx.x * PTM;
  const int j0   = blockIdx.y * PTN;
  const int dir  = (j0 >= 512) ? 1 : 0;
  const int jl0  = j0 - dir*512;
  const float* wih = dir ? wihb : wihf;
  const float* bi  = dir ? bihb : bihf;
  const float* bh  = dir ? bhhb : bhhf;

  const int ty = tid >> 4, tx = tid & 15;
  float acc[8][4];
#pragma unroll
  for (int i=0;i<8;i++)
#pragma unroll
    for (int j=0;j<4;j++) acc[i][j] = 0.f;

  float bias[4];
#pragma unroll
  for (int jj=0;jj<4;jj++){ int jl = jl0 + tx*4 + jj; bias[jj] = bi[jl] + bh[jl]; }

  for (int k0 = 0; k0 < I_; k0 += PTK){
    {
      int r = tid >> 1, kh = (tid & 1) * 16;
      int rg = row0 + r; int bb = rg & 31, tt = rg >> 5;
      const float* ap = x + ((size_t)bb*S_ + tt)*I_ + k0 + kh;
#pragma unroll
      for (int u=0;u<4;u++){
        float4 v = *(const float4*)(ap + u*4);
        As[kh+u*4+0][r] = v.x; As[kh+u*4+1][r] = v.y;
        As[kh+u*4+2][r] = v.z; As[kh+u*4+3][r] = v.w;
      }
    }
    {
      int jr = tid >> 2, kh = (tid & 3) * 8;
      const float* bp = wih + (size_t)(jl0 + jr)*I_ + k0 + kh;
#pragma unroll
      for (int u=0;u<2;u++){
        float4 v = *(const float4*)(bp + u*4);
        Bs[kh+u*4+0][jr] = v.x; Bs[kh+u*4+1][jr] = v.y;
        Bs[kh+u*4+2][jr] = v.z; Bs[kh+u*4+3][jr] = v.w;
      }
    }
    __syncthreads();
#pragma unroll 8
    for (int kk=0; kk<PTK; ++kk){
      const float4 a0 = *(const float4*)&As[kk][ty*8+0];
      const float4 a1 = *(const float4*)&As[kk][ty*8+4];
      const float4 bq = *(const float4*)&Bs[kk][tx*4];
      const float av[8] = {a0.x,a0.y,a0.z,a0.w,a1.x,a1.y,a1.z,a1.w};
      const float bv[4] = {bq.x,bq.y,bq.z,bq.w};
#pragma unroll
      for (int i=0;i<8;i++)
#pragma unroll
        for (int j=0;j<4;j++) acc[i][j] = fmaf(av[i], bv[j], acc[i][j]);
    }
    __syncthreads();
  }
#pragma unroll
  for (int i=0;i<8;i++){
    int rg = row0 + ty*8 + i; int bb = rg & 31, tt = rg >> 5;
    float* op = out + ((size_t)bb*S_ + tt)*OUTW + j0 + tx*4;
    float4 v = {acc[i][0]+bias[0], acc[i][1]+bias[1], acc[i][2]+bias[2], acc[i][3]+bias[3]};
    *(float4*)op = v;
  }
}

// ---------------------------------------------------------------------------
// R: 4-way k-split partial-exchange recurrence.
// 256 WGs x 1024 thr (1/CU, always co-resident). g: chain p = g&63 (dir=p>>5,
// b=p&31), q = g>>6 in [0,4). WG q owns k-cols AND finalize-rows
// [q*128,(q+1)*128) -> its next-step h is exactly what it finalized: the ONLY
// cross-WG traffic is one tagged f16 partial per (row, src) per step.
// Chain's 4 WGs = blocks p+64q -> all same XCD (64q % 8 == 0).
// Lane: sl = tid&7 (k-slice, k = q*128 + sl*16 + [0,16)), jr = tid>>3 in
// [0,128); rows {jr + 128*m, m=0..3}. Weights = 32 dwords/lane (named
// scalars, ~65 live regs: comfortably under the allocator's observed cap).
// Per step: 2 ds_read_b128 (h), 32 fdot2, reduce8, publish (sl<4, sl!=q) or
// spin 3 partner dwords + relu + store (sl==q). One barrier/step.
// ---------------------------------------------------------------------------
#define MAIL_OFF_U32 (1u<<18)        // W f16 = 1 MB = 2^18 u32
#define MAIL_U32     (64*4*2*4*128)  // [chain][dst][parity][src][128] = 1 MB
#define MAIL_BYTES   (MAIL_U32*4)

#define DECL8(Pn) uint32_t Pn##_0,Pn##_1,Pn##_2,Pn##_3,Pn##_4,Pn##_5,Pn##_6,Pn##_7
#define LOAD8(Pn, src) do{ const uint4* _q=(const uint4*)(src); \
  uint4 _a=_q[0], _b=_q[1]; \
  Pn##_0=_a.x; Pn##_1=_a.y; Pn##_2=_a.z; Pn##_3=_a.w; \
  Pn##_4=_b.x; Pn##_5=_b.y; Pn##_6=_b.z; Pn##_7=_b.w; }while(0)
#define KEEP8(Pn) asm volatile("" : \
  "+v"(Pn##_0),"+v"(Pn##_1),"+v"(Pn##_2),"+v"(Pn##_3), \
  "+v"(Pn##_4),"+v"(Pn##_5),"+v"(Pn##_6),"+v"(Pn##_7))
#define DOT8(ACC, Pn) \
  ACC=fdot2(Pn##_0,hv0.x,ACC); ACC=fdot2(Pn##_1,hv0.y,ACC); \
  ACC=fdot2(Pn##_2,hv0.z,ACC); ACC=fdot2(Pn##_3,hv0.w,ACC); \
  ACC=fdot2(Pn##_4,hv1.x,ACC); ACC=fdot2(Pn##_5,hv1.y,ACC); \
  ACC=fdot2(Pn##_6,hv1.z,ACC); ACC=fdot2(Pn##_7,hv1.w,ACC);

__global__ __launch_bounds__(1024) void rnn_kernel(
    const f16* __restrict__ Wall,   // [2][512][512] f16
    const float* __restrict__ h0,   // [2][32][512]
    float* dout, uint32_t* mailbase)
{
  __shared__ char lds[512];         // 2 parity x 128 f16 (own h block)
  const int tid = threadIdx.x;
  const int p   = blockIdx.x & 63;        // chain
  const int q   = blockIdx.x >> 6;        // quarter in [0,4)
  const int dir = p >> 5;
  const int b   = p & 31;
  const int sl  = tid & 7;                // k-slice within quarter
  const int jr  = tid >> 3;               // row group in [0,128)
  const int k3  = sl & 3;

  const f16* Wd = Wall + (size_t)dir * (H_*(size_t)H_);
  float* outs = dout + (size_t)b * (S_*OUTW);
  const int col = dir*512 + q*128 + jr;   // owner lane's output column
  float* hn = dout + (size_t)OUTS_ELEMS + ((size_t)dir*B_ + b) * H_;

  // ---- weights: 4 rows (jr + 128*m) x 16 f16 (k = q*128 + sl*16) = 32 dwords
  DECL8(W0); DECL8(W1); DECL8(W2); DECL8(W3);
  {
    const f16* kb = Wd + q*128 + sl*16;
    LOAD8(W0, kb + (size_t)(jr +   0)*H_);
    LOAD8(W1, kb + (size_t)(jr + 128)*H_);
    LOAD8(W2, kb + (size_t)(jr + 256)*H_);
    LOAD8(W3, kb + (size_t)(jr + 384)*H_);
  }
  KEEP8(W0); KEEP8(W1); KEEP8(W2); KEEP8(W3);   // one-time anti-remat opacity

  // mailbox: dword idx = (((p*4 + dst)*2 + P)*4 + src)*128 + jr
  uint32_t* mb = mailbase;
  const int s0 = (q==0)?1:0, s1 = (q<=1)?2:1, s2 = (q<=2)?3:2;  // our 3 sources

  // ---- stage own h0 block into parity 0
  if (tid < 128){
    *(f16*)(lds + tid*2) = (f16)h0[((size_t)dir*B_ + b)*H_ + q*128 + tid];
  }
  __syncthreads();

  for (int s=0; s<S_; ++s){
    const int P = s & 1;
    const int t = dir ? (S_-1-s) : s;
    float* xo = outs + (size_t)t*OUTW;
    float xpv = 0.f;
    if (sl == q) xpv = xo[col];             // long-latency, hidden by compute

    const char* hb = lds + P*256;
    const uint4 hv0 = *(const uint4*)(hb + sl*32);
    const uint4 hv1 = *(const uint4*)(hb + sl*32 + 16);

    float a0=0.f, a1=0.f, a2=0.f, a3=0.f;
    DOT8(a0, W0) DOT8(a1, W1) DOT8(a2, W2) DOT8(a3, W3)
    const float tot = reduce8(a0,a1,a2,a3,k3);   // row jr + 128*k3, at sl=k3(,+4)

    const uint32_t tag = (uint32_t)(s+1);
    // publish partials for rows finalized by other WGs (program order: before spin)
    if (sl < 4 && sl != q){
      uint16_t pb = __builtin_bit_cast(uint16_t, (f16)tot);
      size_t idx = ((((size_t)p*4 + sl)*2 + P)*4 + q)*128 + jr;
      __hip_atomic_store(&mb[idx], (pb << 16) | tag,
                         __ATOMIC_RELAXED, __HIP_MEMORY_SCOPE_AGENT);
    }
    // finalize own rows: spin on 3 partner partials
    if (sl == q){
      uint32_t* rb = mb + ((((size_t)p*4 + q)*2 + P)*4)*128 + jr;
      uint32_t v0, v1, v2;
      do {
        v0 = __hip_atomic_load(&rb[s0*128], __ATOMIC_RELAXED, __HIP_MEMORY_SCOPE_AGENT);
        v1 = __hip_atomic_load(&rb[s1*128], __ATOMIC_RELAXED, __HIP_MEMORY_SCOPE_AGENT);
        v2 = __hip_atomic_load(&rb[s2*128], __ATOMIC_RELAXED, __HIP_MEMORY_SCOPE_AGENT);
      } while ((((v0 ^ tag) | (v1 ^ tag) | (v2 ^ tag)) & 0xffffu) != 0u);
      float rem = (float)__builtin_bit_cast(f16, (uint16_t)(v0 >> 16))
                + (float)__builtin_bit_cast(f16, (uint16_t)(v1 >> 16))
                + (float)__builtin_bit_cast(f16, (uint16_t)(v2 >> 16));
      float h = fmaxf(xpv + tot + rem, 0.f);
      xo[col] = h;                          // overwrite xp slot with output
      if (s == S_-1) hn[q*128 + jr] = h;
      *(f16*)(lds + (P^1)*256 + jr*2) = (f16)h;   // own h for next step
    }
    asm volatile("s_waitcnt lgkmcnt(0)" ::: "memory");
    __builtin_amdgcn_s_barrier();
  }
}

// ---------------------------------------------------------------------------
extern "C" void kernel_launch(void* const* d_in, const int* in_sizes, int n_in,
                              void* d_out, int out_size, void* d_ws, size_t ws_size,
                              hipStream_t stream){
  const float* x    = (const float*)d_in[0];
  const float* h0   = (const float*)d_in[1];
  const float* wihf = (const float*)d_in[2];
  const float* whhf = (const float*)d_in[3];
  const float* bihf = (const float*)d_in[4];
  const float* bhhf = (const float*)d_in[5];
  const float* wihb = (const float*)d_in[6];
  const float* whhb = (const float*)d_in[7];
  const float* bihb = (const float*)d_in[8];
  const float* bhhb = (const float*)d_in[9];
  float* out = (float*)d_out;
  f16* wf16 = (f16*)d_ws;                            // 1 MB
  uint32_t* mail = (uint32_t*)d_ws + MAIL_OFF_U32;   // 1 MB

  hipMemsetAsync((void*)mail, 0, MAIL_BYTES, stream);  // kill stale tags across replays
  cvt_w_kernel<<<256, 256, 0, stream>>>(whhf, whhb, wf16);
  proj_kernel<<<dim3(128, 16), 256, 0, stream>>>(x, wihf, wihb, bihf, bhhf, bihb, bhhb, out);
  rnn_kernel<<<256, 1024, 0, stream>>>(wf16, h0, out, mail);
}